// Round 10
// baseline (258.652 us; speedup 1.0000x reference)
//
#include <hip/hip_runtime.h>

typedef unsigned short u16;
typedef unsigned int u32;
typedef __attribute__((ext_vector_type(8))) short short8;
typedef __attribute__((ext_vector_type(4))) short short4_t;
typedef __attribute__((ext_vector_type(4))) float floatx4;
typedef __attribute__((ext_vector_type(4))) unsigned short ushort4_t;
typedef __attribute__((ext_vector_type(4))) float float4_t;
typedef __attribute__((ext_vector_type(2))) unsigned int uint2_t;

// ---- helpers ---------------------------------------------------------------

__device__ __forceinline__ u16 f2bf(float f) {
  unsigned u = __builtin_bit_cast(unsigned, f);
  u += 0x7FFFu + ((u >> 16) & 1u);   // RNE; inputs finite
  return (u16)(u >> 16);
}

// pack two fp32 -> bf16x2 via HW cvt_pk (RNE on gfx950): lo16 = a, hi16 = b
__device__ __forceinline__ u32 cvt_pk_bf16(float a, float b) {
  u32 r;
  asm("v_cvt_pk_bf16_f32 %0, %1, %2" : "=v"(r) : "v"(a), "v"(b));
  return r;
}

// async global->LDS, 16B per lane. LDS dest must be wave-uniform base + lane*16.
__device__ __forceinline__ void gload_lds16(const void* g, void* l) {
  __builtin_amdgcn_global_load_lds(
      (const __attribute__((address_space(1))) void*)g,
      (__attribute__((address_space(3))) void*)l, 16, 0, 0);
}

#define BAR __builtin_amdgcn_s_barrier()
#define LGK0                                              \
  do {                                                    \
    asm volatile("s_waitcnt lgkmcnt(0)" ::: "memory");    \
    __builtin_amdgcn_sched_barrier(0);                    \
  } while (0)
#define VM4 asm volatile("s_waitcnt vmcnt(4)" ::: "memory")
#define VM0 asm volatile("s_waitcnt vmcnt(0)" ::: "memory")

// V-scramble: within each 64-elem k-chunk of row d, 4-elem group kappa moves
// to kappa ^ (2*(d&7)) ^ ((d>>3)&1). The parity term makes the 8B-half of a
// lane's va read vary with l16 bit 3 -> ds_read_b64 touches all 32 banks
// within each 16-lane processing group (verified: conflicts 8.65M -> 0).
__device__ __forceinline__ int vscr(int d, int c6) {
  int kp = (c6 >> 2) ^ (2 * (d & 7)) ^ ((d >> 3) & 1);
  return kp * 4 + (c6 & 3);
}

// ---- prep kernels ----------------------------------------------------------

// X fp32 [8192][1024] -> bf16
__global__ void cvt_x(const float* __restrict__ src, u16* __restrict__ dst) {
  int i = blockIdx.x * 256 + threadIdx.x;
  float4_t f = ((const float4_t*)src)[i];
  ushort4_t u;
  u.x = f2bf(f.x); u.y = f2bf(f.y); u.z = f2bf(f.z); u.w = f2bf(f.w);
  ((ushort4_t*)dst)[i] = u;
}

// coalesced LDS-tiled transpose+cvt: W fp32 [K][N] -> bf16 [N][K].
__global__ __launch_bounds__(256) void transpose_cvt4(
    const float* __restrict__ wq, const float* __restrict__ wk,
    const float* __restrict__ wv, const float* __restrict__ wo,
    u16* __restrict__ qk, u16* __restrict__ vt, u16* __restrict__ ot, float sc) {
  __shared__ float T[64][65];
  const int which = blockIdx.z;
  const float* s = (which == 0) ? wq : (which == 1) ? wk : (which == 2) ? wv : wo;
  u16* d = (which == 0) ? qk : (which == 1) ? (qk + (1u << 20)) : (which == 2) ? vt : ot;
  const float scale = (which == 0) ? sc : 1.f;
  const int n0 = blockIdx.x * 64, k0 = blockIdx.y * 64;
  const int c = threadIdx.x & 63, rg = threadIdx.x >> 6;
  for (int i = 0; i < 16; ++i) {
    int r = i * 4 + rg;
    T[r][c] = s[(k0 + r) * 1024 + n0 + c];
  }
  __syncthreads();
  for (int i = 0; i < 16; ++i) {
    int r = i * 4 + rg;
    d[(n0 + r) * 1024 + k0 + c] = f2bf(T[c][r] * scale);
  }
}

// ---- bf16 MFMA GEMM (128^2 m97-structure): for skinny shapes (R9 lesson:
// at 512 full-GPU blocks this beats the 128-block 256^2 kernel for Vt/out).
// MODE 0: bf16 out. MODE 1: f32 out + bias. MODE 2: bf16 out, V-scrambled cols.
template <int MODE>
__global__ __launch_bounds__(256) void gemm_bt(
    const u16* __restrict__ A, const u16* __restrict__ Bt, void* __restrict__ Cv,
    const float* __restrict__ bias, int K, int lda, int ldb, int ldc) {
  __shared__ u16 As[2][128 * 32];
  __shared__ u16 Bs[2][128 * 32];
  const int tid = threadIdx.x;
  const int w = tid >> 6, l = tid & 63, quad = l >> 4, l16 = l & 15;
  const int wm = w >> 1, wn = w & 1;
  const size_t m0 = (size_t)blockIdx.y * 128, n0 = (size_t)blockIdx.x * 128;

  floatx4 acc[4][4];
  for (int i = 0; i < 4; ++i)
    for (int j = 0; j < 4; ++j) acc[i][j] = (floatx4){0.f, 0.f, 0.f, 0.f};

  auto stage = [&](int k0, int buf) {
    for (int i = 0; i < 2; ++i) {
      int c = i * 256 + tid;
      int row = c >> 2, off = (c & 3) * 8;
      gload_lds16(A + (m0 + row) * (size_t)lda + k0 + off, &As[buf][c * 8]);
      gload_lds16(Bt + (n0 + row) * (size_t)ldb + k0 + off, &Bs[buf][c * 8]);
    }
  };

  const int nk = K >> 5;
  stage(0, 0);
  __syncthreads();

  for (int ki = 0; ki < nk; ++ki) {
    const int buf = ki & 1;
    if (ki + 1 < nk) stage((ki + 1) << 5, buf ^ 1);

    short8 a[4], bb[4];
    for (int im = 0; im < 4; ++im)
      a[im] = *(const short8*)&As[buf][(wm * 64 + im * 16 + l16) * 32 + quad * 8];
    for (int in = 0; in < 4; ++in)
      bb[in] = *(const short8*)&Bs[buf][(wn * 64 + in * 16 + l16) * 32 + quad * 8];
    for (int im = 0; im < 4; ++im)
      for (int in = 0; in < 4; ++in)
        acc[im][in] = __builtin_amdgcn_mfma_f32_16x16x32_bf16(a[im], bb[in], acc[im][in], 0, 0, 0);

    __syncthreads();
  }

  for (int im = 0; im < 4; ++im)
    for (int in = 0; in < 4; ++in) {
      size_t r0 = m0 + wm * 64 + im * 16 + quad * 4;
      size_t col = n0 + wn * 64 + in * 16 + l16;
      float bv = (MODE == 1) ? bias[col] : 0.f;
      for (int r = 0; r < 4; ++r) {
        float val = acc[im][in][r] + bv;
        if (MODE == 0) {
          ((u16*)Cv)[(r0 + r) * (size_t)ldc + col] = f2bf(val);
        } else if (MODE == 1) {
          ((float*)Cv)[(r0 + r) * (size_t)ldc + col] = val;
        } else {
          int row = (int)(r0 + r);
          size_t ncol = (col & ~(size_t)63) | (size_t)vscr(row, (int)(col & 63));
          ((u16*)Cv)[row * (size_t)ldc + ncol] = f2bf(val);
        }
      }
    }
}

// ---- bf16 MFMA GEMM, 256^2 8-phase (T1+T2+T3+T4+T5): QK only ---------------
// (R9: best for the fat 256-block QK shape; worse than 128^2 for skinny.)
// vmcnt(0) on last-iter p3 is the race fix for the skipped p2/p3 stages.
template <int MODE, int NTXL>
__global__ __launch_bounds__(512, 2) void gemm256_bt(
    const u16* __restrict__ A, const u16* __restrict__ Bt, void* __restrict__ Cv,
    const float* __restrict__ bias, int K, int lda, int ldb, int ldc) {
  __shared__ u16 As[2][256 * 64];
  __shared__ u16 Bs[2][256 * 64];
  const int tid = threadIdx.x;
  const int l = tid & 63, quad = l >> 4, l16 = l & 15;
  const int w = tid >> 6, wm = w >> 2, wn = w & 3;

  const int nwg = (int)(gridDim.x * gridDim.y);
  const int orig = blockIdx.x + gridDim.x * blockIdx.y;
  const int tsw = (orig & 7) * (nwg >> 3) + (orig >> 3);
  const size_t m0 = (size_t)(tsw >> NTXL) * 256;
  const size_t n0 = (size_t)(tsw & ((1 << NTXL) - 1)) * 256;
  const int NT = K >> 6;

  floatx4 acc[8][4];
#pragma unroll
  for (int i = 0; i < 8; ++i)
#pragma unroll
    for (int j = 0; j < 4; ++j) acc[i][j] = (floatx4){0.f, 0.f, 0.f, 0.f};

  auto stage = [&](int isB, int t, int h) {
    const u16* src = isB ? Bt : A;
    const size_t rb = isB ? n0 : m0;
    const int ld = isB ? ldb : lda;
    u16* lds = (isB ? &Bs[t & 1][0] : &As[t & 1][0]) + h * 8192;
    const int k0 = t << 6;
#pragma unroll
    for (int r = 0; r < 2; ++r) {
      int idx = r * 512 + tid;
      int rr = idx >> 3;
      int ce = ((idx & 7) ^ (rr & 7)) << 3;
      gload_lds16(src + (rb + h * 128 + rr) * (size_t)ld + k0 + ce, lds + idx * 8);
    }
  };

  const int swz = (l16 & 7) << 4;
  const int ca0 = (quad * 16) ^ swz;
  const int ca1 = (64 + quad * 16) ^ swz;
  const char* aB = (const char*)&As[0][0];
  const char* bB = (const char*)&Bs[0][0];
  const int arow = (wm * 128 + l16) * 128;
  const int brow = (wn * 64 + l16) * 128;

  short8 a[4][2], b[2][2][2];

  auto readA = [&](int buf, int mh) {
#pragma unroll
    for (int ii = 0; ii < 4; ++ii) {
      const char* p = aB + buf * 32768 + arow + mh * 8192 + ii * 2048;
      a[ii][0] = *(const short8*)(p + ca0);
      a[ii][1] = *(const short8*)(p + ca1);
    }
  };
  auto readB = [&](int buf, int nh) {
#pragma unroll
    for (int jj = 0; jj < 2; ++jj) {
      const char* p = bB + buf * 32768 + brow + nh * 4096 + jj * 2048;
      b[nh][jj][0] = *(const short8*)(p + ca0);
      b[nh][jj][1] = *(const short8*)(p + ca1);
    }
  };
  auto mmaq = [&](int mh, int nh) {
    __builtin_amdgcn_s_setprio(1);
#pragma unroll
    for (int ii = 0; ii < 4; ++ii)
#pragma unroll
      for (int jj = 0; jj < 2; ++jj) {
        acc[mh * 4 + ii][nh * 2 + jj] = __builtin_amdgcn_mfma_f32_16x16x32_bf16(
            a[ii][0], b[nh][jj][0], acc[mh * 4 + ii][nh * 2 + jj], 0, 0, 0);
        acc[mh * 4 + ii][nh * 2 + jj] = __builtin_amdgcn_mfma_f32_16x16x32_bf16(
            a[ii][1], b[nh][jj][1], acc[mh * 4 + ii][nh * 2 + jj], 0, 0, 0);
      }
    __builtin_amdgcn_s_setprio(0);
  };

  stage(1, 0, 0); stage(1, 0, 1); stage(0, 0, 0); stage(0, 0, 1);
  stage(1, 1, 0); stage(1, 1, 1);
  VM4;
  BAR;

  const int nit = NT >> 1;
  for (int i = 0; i < nit; ++i) {
    const int t0 = 2 * i;
    const bool last = (i + 1 == nit);
    // p0
    readA(0, 0); readB(0, 0);
    stage(0, t0 + 1, 0);
    BAR; LGK0; mmaq(0, 0); BAR;
    // p1
    readB(0, 1);
    stage(0, t0 + 1, 1);
    BAR; LGK0; mmaq(0, 1); BAR;
    // p2
    readA(0, 1);
    if (t0 + 2 < NT) stage(1, t0 + 2, 0);
    BAR; LGK0; mmaq(1, 1); BAR;
    // p3
    if (t0 + 2 < NT) stage(1, t0 + 2, 1);
    mmaq(1, 0);
    if (last) { VM0; } else { VM4; }
    BAR;
    // p4
    readA(1, 0); readB(1, 0);
    if (t0 + 2 < NT) stage(0, t0 + 2, 0);
    BAR; LGK0; mmaq(0, 0); BAR;
    // p5
    readB(1, 1);
    if (t0 + 2 < NT) stage(0, t0 + 2, 1);
    BAR; LGK0; mmaq(0, 1); BAR;
    // p6
    readA(1, 1);
    if (t0 + 3 < NT) stage(1, t0 + 3, 0);
    BAR; LGK0; mmaq(1, 1); BAR;
    // p7
    if (t0 + 3 < NT) stage(1, t0 + 3, 1);
    mmaq(1, 0);
    VM4; BAR;
  }

#pragma unroll
  for (int iF = 0; iF < 8; ++iF)
#pragma unroll
    for (int jF = 0; jF < 4; ++jF) {
      size_t r0 = m0 + wm * 128 + iF * 16 + quad * 4;
      size_t col = n0 + wn * 64 + jF * 16 + l16;
      float bv = (MODE == 1) ? bias[col] : 0.f;
#pragma unroll
      for (int r = 0; r < 4; ++r) {
        float val = acc[iF][jF][r] + bv;
        if (MODE == 0) {
          ((u16*)Cv)[(r0 + r) * (size_t)ldc + col] = f2bf(val);
        } else if (MODE == 1) {
          ((float*)Cv)[(r0 + r) * (size_t)ldc + col] = val;
        } else {
          int row = (int)(r0 + r);
          size_t ncol = (col & ~(size_t)63) | (size_t)vscr(row, (int)(col & 63));
          ((u16*)Cv)[row * (size_t)ldc + ncol] = f2bf(val);
        }
      }
    }
}

// ---- flash attention v7: v6 body + load-balanced qt permutation ------------
// Grid (64 bh, 16 y) = 1024 blocks = EXACTLY residency capacity (4/CU x 8
// waves): all blocks co-resident, so makespan = worst-loaded CU. qt(y) from a
// doubly-balanced magic-square permutation: every stride-4 class AND every
// consecutive-4 group of y sums to 30 steps -> per-CU load ~constant under
// either plausible block->CU assignment granularity (was 56..80 with 15-y).
// Inner body byte-identical to passing v6.
// QK: bf16 [8192][2048] (Q pre-scaled cols 0..1023, K cols 1024..2047).
// Vt: bf16 [1024][8192], V-SCRAMBLED within 64-k chunks (see vscr).
// ctx: bf16 [8192][1024].
// K LDS swizzle: byte(row,col2B) = row*128 + ((2*col) ^ ((row&7)<<4)).
// V LDS: linear copy of scrambled global -> va ds_read_b64 conflict-free.
__global__ __launch_bounds__(512, 4) void flash_attn(
    const u16* __restrict__ QK, const u16* __restrict__ Vt, u16* __restrict__ ctx) {
  __shared__ u16 Ks[2][64 * 64];
  __shared__ u16 Vs[2][64 * 64];

  const int tid = threadIdx.x;
  const int w = tid >> 6, l = tid & 63, quad = l >> 4, l16 = l & 15;
  const int bh = blockIdx.x;
  // magic-square qt permutation: y -> {0,13,11,6,14,3,5,8,7,10,12,1,9,4,2,15}
  const int qt = (int)((0xF2491CA7853E6BD0ull >> (blockIdx.y * 4)) & 0xFull);
  const int b = bh >> 4, h = bh & 15;
  const int xr = (l16 & 7) << 4;
  const int xv = (2 * (l16 & 7)) ^ ((l16 >> 3) & 1);   // V kappa-xor per lane

  const int nkt = 2 * qt + 2;

  auto stage = [&](int kt, int buf) {
    int c = tid;                            // 512 thr x 16B = one 8KB buffer
    int row = c >> 3;
    int scolK = ((c & 7) ^ (row & 7)) << 3;
    gload_lds16(QK + (size_t)(b * 2048 + kt * 64 + row) * 2048 + 1024 + h * 64 + scolK,
                &Ks[buf][c * 8]);
    // V: scramble baked into global layout -> linear source
    gload_lds16(Vt + (size_t)(h * 64 + row) * 8192 + b * 2048 + kt * 64 + ((c & 7) << 3),
                &Vs[buf][c * 8]);
  };

  const int q0w = qt * 128 + w * 16;
  const int ktmax_w = (q0w + 15) >> 6;

  short8 aq[2];
  floatx4 o[4];
  float lsum;
  {
    const size_t base = (size_t)(b * 2048 + q0w + l16) * 2048 + h * 64 + quad * 8;
    aq[0] = *(const short8*)(QK + base);
    aq[1] = *(const short8*)(QK + base + 32);
    lsum = 0.f;
    for (int df = 0; df < 4; ++df) o[df] = (floatx4){0.f, 0.f, 0.f, 0.f};
  }

  stage(0, 0);
  __syncthreads();

  for (int kt = 0; kt < nkt; ++kt) {
    const int buf = kt & 1;
    if (kt + 1 < nkt) stage(kt + 1, buf ^ 1);

    if (kt <= ktmax_w) {
      const bool need_mask = (kt == ktmax_w);

      short8 ka[4][2];
      for (int nf = 0; nf < 4; ++nf) {
        const char* kb = (const char*)&Ks[buf][0] + (nf * 16 + l16) * 128;
        ka[nf][0] = *(const short8*)(kb + ((quad * 16) ^ xr));
        ka[nf][1] = *(const short8*)(kb + ((64 + quad * 16) ^ xr));
      }

      floatx4 s[4];
      for (int nf = 0; nf < 4; ++nf) s[nf] = (floatx4){0.f, 0.f, 0.f, 0.f};
      __builtin_amdgcn_s_setprio(1);
      for (int nf = 0; nf < 4; ++nf) {
        s[nf] = __builtin_amdgcn_mfma_f32_16x16x32_bf16(ka[nf][0], aq[0], s[nf], 0, 0, 0);
        s[nf] = __builtin_amdgcn_mfma_f32_16x16x32_bf16(ka[nf][1], aq[1], s[nf], 0, 0, 0);
      }
      __builtin_amdgcn_s_setprio(0);
      if (need_mask) {
        int qpos = q0w + l16;
        for (int nf = 0; nf < 4; ++nf)
          for (int r = 0; r < 4; ++r) {
            int kpos = kt * 64 + nf * 16 + quad * 4 + r;
            if (kpos > qpos) s[nf][r] = -1e30f;
          }
      }
      for (int nf = 0; nf < 4; ++nf) {
        // V^T A-frags: lane holds Vs[d = df*16+l16][k = nf*16 + quad*4 + j]
        // at scrambled byte offset ((nf*4+quad) ^ xv) * 8.
        const int kpp = ((nf * 4 + quad) ^ xv) << 3;
        short4_t va[4];
        for (int df = 0; df < 4; ++df) {
          const char* vb = (const char*)&Vs[buf][0] + (df * 16 + l16) * 128;
          va[df] = *(const short4_t*)(vb + kpp);
        }
        float p0 = __builtin_amdgcn_exp2f(s[nf][0]);
        float p1 = __builtin_amdgcn_exp2f(s[nf][1]);
        float p2 = __builtin_amdgcn_exp2f(s[nf][2]);
        float p3 = __builtin_amdgcn_exp2f(s[nf][3]);
        lsum += (p0 + p1) + (p2 + p3);
        uint2_t pk;
        pk.x = cvt_pk_bf16(p0, p1);   // lo16 = p0 (j even), hi = p1
        pk.y = cvt_pk_bf16(p2, p3);
        short4_t pb = __builtin_bit_cast(short4_t, pk);  // B-frag of 16x16x16
        __builtin_amdgcn_s_setprio(1);
        for (int df = 0; df < 4; ++df)
          o[df] = __builtin_amdgcn_mfma_f32_16x16x16bf16_1k(va[df], pb, o[df], 0, 0, 0);
        __builtin_amdgcn_s_setprio(0);
      }
    }
    __syncthreads();
  }

  {
    float t = lsum;
    t += __shfl_xor(t, 16, 64);
    t += __shfl_xor(t, 32, 64);
    float inv = __builtin_amdgcn_rcpf(t);
    // o^T: lane q = l16, d = df*16 + quad*4 + r  -> in-lane normalize
    size_t row = (size_t)(b * 2048 + q0w + l16);
    for (int df = 0; df < 4; ++df) {
      ushort4_t st;
      for (int r = 0; r < 4; ++r) st[r] = f2bf(o[df][r] * inv);
      *(ushort4_t*)(ctx + row * 1024 + h * 64 + df * 16 + quad * 4) = st;
    }
  }
}

// ---- launch ----------------------------------------------------------------

extern "C" void kernel_launch(void* const* d_in, const int* in_sizes, int n_in,
                              void* d_out, int out_size, void* d_ws, size_t ws_size,
                              hipStream_t stream) {
  const float* X  = (const float*)d_in[0];
  const float* Wq = (const float*)d_in[1];
  const float* Wk = (const float*)d_in[2];
  const float* Wv = (const float*)d_in[3];
  const float* Wo = (const float*)d_in[4];
  const float* bo = (const float*)d_in[5];

  char* ws = (char*)d_ws;
  u16* Xb   = (u16*)(ws);                  // 16 MiB; later overwritten with ctx
  u16* WqkT = (u16*)(ws + (16u << 20));    // 4 MiB: [Wq^T(scaled) ; Wk^T]
  u16* WvT  = (u16*)(ws + (20u << 20));    // 2 MiB
  u16* WoT  = (u16*)(ws + (22u << 20));    // 2 MiB
  u16* QKb  = (u16*)(ws + (24u << 20));    // 32 MiB: [8192][2048]
  u16* Vt   = (u16*)(ws + (56u << 20));    // 16 MiB: [1024][8192] (V-scrambled)

  const float SC = 0.125f * 1.44269504088896340736f;  // 1/sqrt(64) * log2(e)

  cvt_x<<<8192, 256, 0, stream>>>(X, Xb);
  transpose_cvt4<<<dim3(16, 16, 4), 256, 0, stream>>>(Wq, Wk, Wv, Wo, WqkT, WvT, WoT, SC);

  // [Q K] = Xb @ [Wq Wk] : [8192][2048]  -- 256^2 8-phase, 256 blocks
  gemm256_bt<0, 3><<<dim3(8, 32), 512, 0, stream>>>(
      Xb, WqkT, QKb, nullptr, 1024, 1024, 1024, 2048);
  // Vt = (Xb @ Wv)^T : [1024][8192], V-scrambled -- 128^2, 512 blocks (R9 fix)
  gemm_bt<2><<<dim3(64, 8), 256, 0, stream>>>(WvT, Xb, Vt, nullptr, 1024, 1024, 1024, 8192);

  // causal flash attention v7 (balanced qt permutation); ctx overwrites Xb
  flash_attn<<<dim3(64, 16), 512, 0, stream>>>(QKb, Vt, Xb);

  // out = ctx @ Wo + bo : fp32 -- 128^2, 512 blocks (R9 fix)
  gemm_bt<1><<<dim3(8, 64), 256, 0, stream>>>(Xb, WoT, (float*)d_out, bo, 1024, 1024, 1024, 1024);
}

// Round 11
// 243.640 us; speedup vs baseline: 1.0616x; 1.0616x over previous
//
#include <hip/hip_runtime.h>

typedef unsigned short u16;
typedef unsigned int u32;
typedef __attribute__((ext_vector_type(8))) short short8;
typedef __attribute__((ext_vector_type(4))) short short4_t;
typedef __attribute__((ext_vector_type(4))) float floatx4;
typedef __attribute__((ext_vector_type(4))) unsigned short ushort4_t;
typedef __attribute__((ext_vector_type(4))) float float4_t;
typedef __attribute__((ext_vector_type(2))) unsigned int uint2_t;

// ---- helpers ---------------------------------------------------------------

__device__ __forceinline__ u16 f2bf(float f) {
  unsigned u = __builtin_bit_cast(unsigned, f);
  u += 0x7FFFu + ((u >> 16) & 1u);   // RNE; inputs finite
  return (u16)(u >> 16);
}

// pack two fp32 -> bf16x2 via HW cvt_pk (RNE on gfx950): lo16 = a, hi16 = b
__device__ __forceinline__ u32 cvt_pk_bf16(float a, float b) {
  u32 r;
  asm("v_cvt_pk_bf16_f32 %0, %1, %2" : "=v"(r) : "v"(a), "v"(b));
  return r;
}

// async global->LDS, 16B per lane. LDS dest must be wave-uniform base + lane*16.
__device__ __forceinline__ void gload_lds16(const void* g, void* l) {
  __builtin_amdgcn_global_load_lds(
      (const __attribute__((address_space(1))) void*)g,
      (__attribute__((address_space(3))) void*)l, 16, 0, 0);
}

#define BAR __builtin_amdgcn_s_barrier()
#define LGK0                                              \
  do {                                                    \
    asm volatile("s_waitcnt lgkmcnt(0)" ::: "memory");    \
    __builtin_amdgcn_sched_barrier(0);                    \
  } while (0)
#define VM4 asm volatile("s_waitcnt vmcnt(4)" ::: "memory")
#define VM0 asm volatile("s_waitcnt vmcnt(0)" ::: "memory")

// V-scramble: within each 64-elem k-chunk of row d, 4-elem group kappa moves
// to kappa ^ (2*(d&7)) ^ ((d>>3)&1). The parity term makes the 8B-half of a
// lane's va read vary with l16 bit 3 -> ds_read_b64 touches all 32 banks
// within each 16-lane processing group (verified: conflicts 8.65M -> 0).
__device__ __forceinline__ int vscr(int d, int c6) {
  int kp = (c6 >> 2) ^ (2 * (d & 7)) ^ ((d >> 3) & 1);
  return kp * 4 + (c6 & 3);
}

// ---- prep kernels ----------------------------------------------------------

// X fp32 [8192][1024] -> bf16
__global__ void cvt_x(const float* __restrict__ src, u16* __restrict__ dst) {
  int i = blockIdx.x * 256 + threadIdx.x;
  float4_t f = ((const float4_t*)src)[i];
  ushort4_t u;
  u.x = f2bf(f.x); u.y = f2bf(f.y); u.z = f2bf(f.z); u.w = f2bf(f.w);
  ((ushort4_t*)dst)[i] = u;
}

// coalesced LDS-tiled transpose+cvt: W fp32 [K][N] -> bf16 [N][K].
__global__ __launch_bounds__(256) void transpose_cvt4(
    const float* __restrict__ wq, const float* __restrict__ wk,
    const float* __restrict__ wv, const float* __restrict__ wo,
    u16* __restrict__ qk, u16* __restrict__ vt, u16* __restrict__ ot, float sc) {
  __shared__ float T[64][65];
  const int which = blockIdx.z;
  const float* s = (which == 0) ? wq : (which == 1) ? wk : (which == 2) ? wv : wo;
  u16* d = (which == 0) ? qk : (which == 1) ? (qk + (1u << 20)) : (which == 2) ? vt : ot;
  const float scale = (which == 0) ? sc : 1.f;
  const int n0 = blockIdx.x * 64, k0 = blockIdx.y * 64;
  const int c = threadIdx.x & 63, rg = threadIdx.x >> 6;
  for (int i = 0; i < 16; ++i) {
    int r = i * 4 + rg;
    T[r][c] = s[(k0 + r) * 1024 + n0 + c];
  }
  __syncthreads();
  for (int i = 0; i < 16; ++i) {
    int r = i * 4 + rg;
    d[(n0 + r) * 1024 + k0 + c] = f2bf(T[c][r] * scale);
  }
}

// ---- bf16 MFMA GEMM (128^2 m97-structure): for skinny shapes (R9 lesson:
// at 512 full-GPU blocks this beats the 128-block 256^2 kernel for Vt/out).
// MODE 0: bf16 out. MODE 1: f32 out + bias. MODE 2: bf16 out, V-scrambled cols.
template <int MODE>
__global__ __launch_bounds__(256) void gemm_bt(
    const u16* __restrict__ A, const u16* __restrict__ Bt, void* __restrict__ Cv,
    const float* __restrict__ bias, int K, int lda, int ldb, int ldc) {
  __shared__ u16 As[2][128 * 32];
  __shared__ u16 Bs[2][128 * 32];
  const int tid = threadIdx.x;
  const int w = tid >> 6, l = tid & 63, quad = l >> 4, l16 = l & 15;
  const int wm = w >> 1, wn = w & 1;
  const size_t m0 = (size_t)blockIdx.y * 128, n0 = (size_t)blockIdx.x * 128;

  floatx4 acc[4][4];
  for (int i = 0; i < 4; ++i)
    for (int j = 0; j < 4; ++j) acc[i][j] = (floatx4){0.f, 0.f, 0.f, 0.f};

  auto stage = [&](int k0, int buf) {
    for (int i = 0; i < 2; ++i) {
      int c = i * 256 + tid;
      int row = c >> 2, off = (c & 3) * 8;
      gload_lds16(A + (m0 + row) * (size_t)lda + k0 + off, &As[buf][c * 8]);
      gload_lds16(Bt + (n0 + row) * (size_t)ldb + k0 + off, &Bs[buf][c * 8]);
    }
  };

  const int nk = K >> 5;
  stage(0, 0);
  __syncthreads();

  for (int ki = 0; ki < nk; ++ki) {
    const int buf = ki & 1;
    if (ki + 1 < nk) stage((ki + 1) << 5, buf ^ 1);

    short8 a[4], bb[4];
    for (int im = 0; im < 4; ++im)
      a[im] = *(const short8*)&As[buf][(wm * 64 + im * 16 + l16) * 32 + quad * 8];
    for (int in = 0; in < 4; ++in)
      bb[in] = *(const short8*)&Bs[buf][(wn * 64 + in * 16 + l16) * 32 + quad * 8];
    for (int im = 0; im < 4; ++im)
      for (int in = 0; in < 4; ++in)
        acc[im][in] = __builtin_amdgcn_mfma_f32_16x16x32_bf16(a[im], bb[in], acc[im][in], 0, 0, 0);

    __syncthreads();
  }

  for (int im = 0; im < 4; ++im)
    for (int in = 0; in < 4; ++in) {
      size_t r0 = m0 + wm * 64 + im * 16 + quad * 4;
      size_t col = n0 + wn * 64 + in * 16 + l16;
      float bv = (MODE == 1) ? bias[col] : 0.f;
      for (int r = 0; r < 4; ++r) {
        float val = acc[im][in][r] + bv;
        if (MODE == 0) {
          ((u16*)Cv)[(r0 + r) * (size_t)ldc + col] = f2bf(val);
        } else if (MODE == 1) {
          ((float*)Cv)[(r0 + r) * (size_t)ldc + col] = val;
        } else {
          int row = (int)(r0 + r);
          size_t ncol = (col & ~(size_t)63) | (size_t)vscr(row, (int)(col & 63));
          ((u16*)Cv)[row * (size_t)ldc + ncol] = f2bf(val);
        }
      }
    }
}

// ---- bf16 MFMA GEMM, 256^2 8-phase (T1+T2+T3+T4+T5): QK only ---------------
// (R9: best for the fat 256-block QK shape; worse than 128^2 for skinny.)
// vmcnt(0) on last-iter p3 is the race fix for the skipped p2/p3 stages.
__global__ __launch_bounds__(512, 2) void gemm256_bt(
    const u16* __restrict__ A, const u16* __restrict__ Bt, u16* __restrict__ C,
    int K, int lda, int ldb, int ldc) {
  __shared__ u16 As[2][256 * 64];
  __shared__ u16 Bs[2][256 * 64];
  const int tid = threadIdx.x;
  const int l = tid & 63, quad = l >> 4, l16 = l & 15;
  const int w = tid >> 6, wm = w >> 2, wn = w & 3;

  const int orig = blockIdx.x + 8 * blockIdx.y;
  const int tsw = (orig & 7) * 32 + (orig >> 3);
  const size_t m0 = (size_t)(tsw >> 3) * 256, n0 = (size_t)(tsw & 7) * 256;
  const int NT = K >> 6;

  floatx4 acc[8][4];
#pragma unroll
  for (int i = 0; i < 8; ++i)
#pragma unroll
    for (int j = 0; j < 4; ++j) acc[i][j] = (floatx4){0.f, 0.f, 0.f, 0.f};

  auto stage = [&](int isB, int t, int h) {
    const u16* src = isB ? Bt : A;
    const size_t rb = isB ? n0 : m0;
    const int ld = isB ? ldb : lda;
    u16* lds = (isB ? &Bs[t & 1][0] : &As[t & 1][0]) + h * 8192;
    const int k0 = t << 6;
#pragma unroll
    for (int r = 0; r < 2; ++r) {
      int idx = r * 512 + tid;
      int rr = idx >> 3;
      int ce = ((idx & 7) ^ (rr & 7)) << 3;
      gload_lds16(src + (rb + h * 128 + rr) * (size_t)ld + k0 + ce, lds + idx * 8);
    }
  };

  const int swz = (l16 & 7) << 4;
  const int ca0 = (quad * 16) ^ swz;
  const int ca1 = (64 + quad * 16) ^ swz;
  const char* aB = (const char*)&As[0][0];
  const char* bB = (const char*)&Bs[0][0];
  const int arow = (wm * 128 + l16) * 128;
  const int brow = (wn * 64 + l16) * 128;

  short8 a[4][2], b[2][2][2];

  auto readA = [&](int buf, int mh) {
#pragma unroll
    for (int ii = 0; ii < 4; ++ii) {
      const char* p = aB + buf * 32768 + arow + mh * 8192 + ii * 2048;
      a[ii][0] = *(const short8*)(p + ca0);
      a[ii][1] = *(const short8*)(p + ca1);
    }
  };
  auto readB = [&](int buf, int nh) {
#pragma unroll
    for (int jj = 0; jj < 2; ++jj) {
      const char* p = bB + buf * 32768 + brow + nh * 4096 + jj * 2048;
      b[nh][jj][0] = *(const short8*)(p + ca0);
      b[nh][jj][1] = *(const short8*)(p + ca1);
    }
  };
  auto mmaq = [&](int mh, int nh) {
    __builtin_amdgcn_s_setprio(1);
#pragma unroll
    for (int ii = 0; ii < 4; ++ii)
#pragma unroll
      for (int jj = 0; jj < 2; ++jj) {
        acc[mh * 4 + ii][nh * 2 + jj] = __builtin_amdgcn_mfma_f32_16x16x32_bf16(
            a[ii][0], b[nh][jj][0], acc[mh * 4 + ii][nh * 2 + jj], 0, 0, 0);
        acc[mh * 4 + ii][nh * 2 + jj] = __builtin_amdgcn_mfma_f32_16x16x32_bf16(
            a[ii][1], b[nh][jj][1], acc[mh * 4 + ii][nh * 2 + jj], 0, 0, 0);
      }
    __builtin_amdgcn_s_setprio(0);
  };

  stage(1, 0, 0); stage(1, 0, 1); stage(0, 0, 0); stage(0, 0, 1);
  stage(1, 1, 0); stage(1, 1, 1);
  VM4;
  BAR;

  const int nit = NT >> 1;
  for (int i = 0; i < nit; ++i) {
    const int t0 = 2 * i;
    const bool last = (i + 1 == nit);
    // p0
    readA(0, 0); readB(0, 0);
    stage(0, t0 + 1, 0);
    BAR; LGK0; mmaq(0, 0); BAR;
    // p1
    readB(0, 1);
    stage(0, t0 + 1, 1);
    BAR; LGK0; mmaq(0, 1); BAR;
    // p2
    readA(0, 1);
    if (t0 + 2 < NT) stage(1, t0 + 2, 0);
    BAR; LGK0; mmaq(1, 1); BAR;
    // p3
    if (t0 + 2 < NT) stage(1, t0 + 2, 1);
    mmaq(1, 0);
    if (last) { VM0; } else { VM4; }
    BAR;
    // p4
    readA(1, 0); readB(1, 0);
    if (t0 + 2 < NT) stage(0, t0 + 2, 0);
    BAR; LGK0; mmaq(0, 0); BAR;
    // p5
    readB(1, 1);
    if (t0 + 2 < NT) stage(0, t0 + 2, 1);
    BAR; LGK0; mmaq(0, 1); BAR;
    // p6
    readA(1, 1);
    if (t0 + 3 < NT) stage(1, t0 + 3, 0);
    BAR; LGK0; mmaq(1, 1); BAR;
    // p7
    if (t0 + 3 < NT) stage(1, t0 + 3, 1);
    mmaq(1, 0);
    VM4; BAR;
  }

#pragma unroll
  for (int iF = 0; iF < 8; ++iF)
#pragma unroll
    for (int jF = 0; jF < 4; ++jF) {
      size_t r0 = m0 + wm * 128 + iF * 16 + quad * 4;
      size_t col = n0 + wn * 64 + jF * 16 + l16;
#pragma unroll
      for (int r = 0; r < 4; ++r)
        C[(r0 + r) * (size_t)ldc + col] = f2bf(acc[iF][jF][r]);
    }
}

// ---- flash attention v6 (R7-proven, 56.2-56.9 us): 8 waves x 16 q ----------
// grid (64 bh, 16 y) = 1024 blocks; qt = 15 - y: LONGEST BLOCKS DISPATCH
// FIRST (LPT). R10 lesson: a "balanced" qt permutation that launches long
// blocks late costs +33% (straggler tail, Occ 48->26, FETCH +24%). Dispatch
// order IS the load balancer; do not permute.
// QK: bf16 [8192][2048] (Q pre-scaled cols 0..1023, K cols 1024..2047).
// Vt: bf16 [1024][8192], V-SCRAMBLED within 64-k chunks (see vscr).
// ctx: bf16 [8192][1024].
// K LDS swizzle: byte(row,col2B) = row*128 + ((2*col) ^ ((row&7)<<4)).
// V LDS: linear copy of scrambled global -> va ds_read_b64 conflict-free.
__global__ __launch_bounds__(512, 4) void flash_attn(
    const u16* __restrict__ QK, const u16* __restrict__ Vt, u16* __restrict__ ctx) {
  __shared__ u16 Ks[2][64 * 64];
  __shared__ u16 Vs[2][64 * 64];

  const int tid = threadIdx.x;
  const int w = tid >> 6, l = tid & 63, quad = l >> 4, l16 = l & 15;
  const int bh = blockIdx.x;
  const int qt = 15 - blockIdx.y;           // descending: long blocks first
  const int b = bh >> 4, h = bh & 15;
  const int xr = (l16 & 7) << 4;
  const int xv = (2 * (l16 & 7)) ^ ((l16 >> 3) & 1);   // V kappa-xor per lane

  const int nkt = 2 * qt + 2;

  auto stage = [&](int kt, int buf) {
    int c = tid;                            // 512 thr x 16B = one 8KB buffer
    int row = c >> 3;
    int scolK = ((c & 7) ^ (row & 7)) << 3;
    gload_lds16(QK + (size_t)(b * 2048 + kt * 64 + row) * 2048 + 1024 + h * 64 + scolK,
                &Ks[buf][c * 8]);
    // V: scramble baked into global layout -> linear source
    gload_lds16(Vt + (size_t)(h * 64 + row) * 8192 + b * 2048 + kt * 64 + ((c & 7) << 3),
                &Vs[buf][c * 8]);
  };

  const int q0w = qt * 128 + w * 16;
  const int ktmax_w = (q0w + 15) >> 6;

  short8 aq[2];
  floatx4 o[4];
  float lsum;
  {
    const size_t base = (size_t)(b * 2048 + q0w + l16) * 2048 + h * 64 + quad * 8;
    aq[0] = *(const short8*)(QK + base);
    aq[1] = *(const short8*)(QK + base + 32);
    lsum = 0.f;
    for (int df = 0; df < 4; ++df) o[df] = (floatx4){0.f, 0.f, 0.f, 0.f};
  }

  stage(0, 0);
  __syncthreads();

  for (int kt = 0; kt < nkt; ++kt) {
    const int buf = kt & 1;
    if (kt + 1 < nkt) stage(kt + 1, buf ^ 1);

    if (kt <= ktmax_w) {
      const bool need_mask = (kt == ktmax_w);

      short8 ka[4][2];
      for (int nf = 0; nf < 4; ++nf) {
        const char* kb = (const char*)&Ks[buf][0] + (nf * 16 + l16) * 128;
        ka[nf][0] = *(const short8*)(kb + ((quad * 16) ^ xr));
        ka[nf][1] = *(const short8*)(kb + ((64 + quad * 16) ^ xr));
      }

      floatx4 s[4];
      for (int nf = 0; nf < 4; ++nf) s[nf] = (floatx4){0.f, 0.f, 0.f, 0.f};
      __builtin_amdgcn_s_setprio(1);
      for (int nf = 0; nf < 4; ++nf) {
        s[nf] = __builtin_amdgcn_mfma_f32_16x16x32_bf16(ka[nf][0], aq[0], s[nf], 0, 0, 0);
        s[nf] = __builtin_amdgcn_mfma_f32_16x16x32_bf16(ka[nf][1], aq[1], s[nf], 0, 0, 0);
      }
      __builtin_amdgcn_s_setprio(0);
      if (need_mask) {
        int qpos = q0w + l16;
        for (int nf = 0; nf < 4; ++nf)
          for (int r = 0; r < 4; ++r) {
            int kpos = kt * 64 + nf * 16 + quad * 4 + r;
            if (kpos > qpos) s[nf][r] = -1e30f;
          }
      }
      for (int nf = 0; nf < 4; ++nf) {
        // V^T A-frags: lane holds Vs[d = df*16+l16][k = nf*16 + quad*4 + j]
        // at scrambled byte offset ((nf*4+quad) ^ xv) * 8.
        const int kpp = ((nf * 4 + quad) ^ xv) << 3;
        short4_t va[4];
        for (int df = 0; df < 4; ++df) {
          const char* vb = (const char*)&Vs[buf][0] + (df * 16 + l16) * 128;
          va[df] = *(const short4_t*)(vb + kpp);
        }
        float p0 = __builtin_amdgcn_exp2f(s[nf][0]);
        float p1 = __builtin_amdgcn_exp2f(s[nf][1]);
        float p2 = __builtin_amdgcn_exp2f(s[nf][2]);
        float p3 = __builtin_amdgcn_exp2f(s[nf][3]);
        lsum += (p0 + p1) + (p2 + p3);
        uint2_t pk;
        pk.x = cvt_pk_bf16(p0, p1);   // lo16 = p0 (j even), hi = p1
        pk.y = cvt_pk_bf16(p2, p3);
        short4_t pb = __builtin_bit_cast(short4_t, pk);  // B-frag of 16x16x16
        __builtin_amdgcn_s_setprio(1);
        for (int df = 0; df < 4; ++df)
          o[df] = __builtin_amdgcn_mfma_f32_16x16x16bf16_1k(va[df], pb, o[df], 0, 0, 0);
        __builtin_amdgcn_s_setprio(0);
      }
    }
    __syncthreads();
  }

  {
    float t = lsum;
    t += __shfl_xor(t, 16, 64);
    t += __shfl_xor(t, 32, 64);
    float inv = __builtin_amdgcn_rcpf(t);
    // o^T: lane q = l16, d = df*16 + quad*4 + r  -> in-lane normalize
    size_t row = (size_t)(b * 2048 + q0w + l16);
    for (int df = 0; df < 4; ++df) {
      ushort4_t st;
      for (int r = 0; r < 4; ++r) st[r] = f2bf(o[df][r] * inv);
      *(ushort4_t*)(ctx + row * 1024 + h * 64 + df * 16 + quad * 4) = st;
    }
  }
}

// ---- launch ----------------------------------------------------------------

extern "C" void kernel_launch(void* const* d_in, const int* in_sizes, int n_in,
                              void* d_out, int out_size, void* d_ws, size_t ws_size,
                              hipStream_t stream) {
  const float* X  = (const float*)d_in[0];
  const float* Wq = (const float*)d_in[1];
  const float* Wk = (const float*)d_in[2];
  const float* Wv = (const float*)d_in[3];
  const float* Wo = (const float*)d_in[4];
  const float* bo = (const float*)d_in[5];

  char* ws = (char*)d_ws;
  u16* Xb   = (u16*)(ws);                  // 16 MiB; later overwritten with ctx
  u16* WqkT = (u16*)(ws + (16u << 20));    // 4 MiB: [Wq^T(scaled) ; Wk^T]
  u16* WvT  = (u16*)(ws + (20u << 20));    // 2 MiB
  u16* WoT  = (u16*)(ws + (22u << 20));    // 2 MiB
  u16* QKb  = (u16*)(ws + (24u << 20));    // 32 MiB: [8192][2048]
  u16* Vt   = (u16*)(ws + (56u << 20));    // 16 MiB: [1024][8192] (V-scrambled)

  const float SC = 0.125f * 1.44269504088896340736f;  // 1/sqrt(64) * log2(e)

  cvt_x<<<8192, 256, 0, stream>>>(X, Xb);
  transpose_cvt4<<<dim3(16, 16, 4), 256, 0, stream>>>(Wq, Wk, Wv, Wo, WqkT, WvT, WoT, SC);

  // [Q K] = Xb @ [Wq Wk] : [8192][2048]  -- 256^2 8-phase, 256 blocks
  gemm256_bt<<<dim3(8, 32), 512, 0, stream>>>(Xb, WqkT, QKb, 1024, 1024, 1024, 2048);
  // Vt = (Xb @ Wv)^T : [1024][8192], V-scrambled -- 128^2, 512 blocks
  gemm_bt<2><<<dim3(64, 8), 256, 0, stream>>>(WvT, Xb, Vt, nullptr, 1024, 1024, 1024, 8192);

  // causal flash attention v6 (longest-first dispatch); ctx overwrites Xb
  flash_attn<<<dim3(64, 16), 512, 0, stream>>>(QKb, Vt, Xb);

  // out = ctx @ Wo + bo : fp32 -- 128^2, 512 blocks
  gemm_bt<1><<<dim3(8, 64), 256, 0, stream>>>(Xb, WoT, (float*)d_out, bo, 1024, 1024, 1024, 1024);
}

// Round 13
// 239.045 us; speedup vs baseline: 1.0820x; 1.0192x over previous
//
#include <hip/hip_runtime.h>

typedef unsigned short u16;
typedef unsigned int u32;
typedef __attribute__((ext_vector_type(8))) short short8;
typedef __attribute__((ext_vector_type(4))) short short4_t;
typedef __attribute__((ext_vector_type(4))) float floatx4;
typedef __attribute__((ext_vector_type(4))) unsigned short ushort4_t;
typedef __attribute__((ext_vector_type(4))) float float4_t;
typedef __attribute__((ext_vector_type(2))) unsigned int uint2_t;

// ---- helpers ---------------------------------------------------------------

__device__ __forceinline__ u16 f2bf(float f) {
  unsigned u = __builtin_bit_cast(unsigned, f);
  u += 0x7FFFu + ((u >> 16) & 1u);   // RNE; inputs finite
  return (u16)(u >> 16);
}

// pack two fp32 -> bf16x2 via HW cvt_pk (RNE on gfx950): lo16 = a, hi16 = b
__device__ __forceinline__ u32 cvt_pk_bf16(float a, float b) {
  u32 r;
  asm("v_cvt_pk_bf16_f32 %0, %1, %2" : "=v"(r) : "v"(a), "v"(b));
  return r;
}

// async global->LDS, 16B per lane. LDS dest must be wave-uniform base + lane*16.
__device__ __forceinline__ void gload_lds16(const void* g, void* l) {
  __builtin_amdgcn_global_load_lds(
      (const __attribute__((address_space(1))) void*)g,
      (__attribute__((address_space(3))) void*)l, 16, 0, 0);
}

#define BAR __builtin_amdgcn_s_barrier()
#define LGK0                                              \
  do {                                                    \
    asm volatile("s_waitcnt lgkmcnt(0)" ::: "memory");    \
    __builtin_amdgcn_sched_barrier(0);                    \
  } while (0)
#define VM4 asm volatile("s_waitcnt vmcnt(4)" ::: "memory")
#define VM2 asm volatile("s_waitcnt vmcnt(2)" ::: "memory")
#define VM0 asm volatile("s_waitcnt vmcnt(0)" ::: "memory")

// V-scramble: within each 64-elem k-chunk of row d, 4-elem group kappa moves
// to kappa ^ (2*(d&7)) ^ ((d>>3)&1). The parity term makes the 8B-half of a
// lane's va read vary with l16 bit 3 -> ds_read_b64 touches all 32 banks
// within each 16-lane processing group (verified: conflicts 8.65M -> 0).
__device__ __forceinline__ int vscr(int d, int c6) {
  int kp = (c6 >> 2) ^ (2 * (d & 7)) ^ ((d >> 3) & 1);
  return kp * 4 + (c6 & 3);
}

// ---- prep kernels ----------------------------------------------------------

// X fp32 [8192][1024] -> bf16
__global__ void cvt_x(const float* __restrict__ src, u16* __restrict__ dst) {
  int i = blockIdx.x * 256 + threadIdx.x;
  float4_t f = ((const float4_t*)src)[i];
  ushort4_t u;
  u.x = f2bf(f.x); u.y = f2bf(f.y); u.z = f2bf(f.z); u.w = f2bf(f.w);
  ((ushort4_t*)dst)[i] = u;
}

// coalesced LDS-tiled transpose+cvt: W fp32 [K][N] -> bf16 [N][K].
__global__ __launch_bounds__(256) void transpose_cvt4(
    const float* __restrict__ wq, const float* __restrict__ wk,
    const float* __restrict__ wv, const float* __restrict__ wo,
    u16* __restrict__ qk, u16* __restrict__ vt, u16* __restrict__ ot, float sc) {
  __shared__ float T[64][65];
  const int which = blockIdx.z;
  const float* s = (which == 0) ? wq : (which == 1) ? wk : (which == 2) ? wv : wo;
  u16* d = (which == 0) ? qk : (which == 1) ? (qk + (1u << 20)) : (which == 2) ? vt : ot;
  const float scale = (which == 0) ? sc : 1.f;
  const int n0 = blockIdx.x * 64, k0 = blockIdx.y * 64;
  const int c = threadIdx.x & 63, rg = threadIdx.x >> 6;
  for (int i = 0; i < 16; ++i) {
    int r = i * 4 + rg;
    T[r][c] = s[(k0 + r) * 1024 + n0 + c];
  }
  __syncthreads();
  for (int i = 0; i < 16; ++i) {
    int r = i * 4 + rg;
    d[(n0 + r) * 1024 + k0 + c] = f2bf(T[c][r] * scale);
  }
}

// ---- bf16 MFMA GEMM (128^2 m97-structure): for skinny shapes (R9 lesson:
// at 512 full-GPU blocks this beats the 128-block 256^2 kernel for Vt/out).
// MODE 0: bf16 out. MODE 1: f32 out + bias. MODE 2: bf16 out, V-scrambled cols.
template <int MODE>
__global__ __launch_bounds__(256) void gemm_bt(
    const u16* __restrict__ A, const u16* __restrict__ Bt, void* __restrict__ Cv,
    const float* __restrict__ bias, int K, int lda, int ldb, int ldc) {
  __shared__ u16 As[2][128 * 32];
  __shared__ u16 Bs[2][128 * 32];
  const int tid = threadIdx.x;
  const int w = tid >> 6, l = tid & 63, quad = l >> 4, l16 = l & 15;
  const int wm = w >> 1, wn = w & 1;
  const size_t m0 = (size_t)blockIdx.y * 128, n0 = (size_t)blockIdx.x * 128;

  floatx4 acc[4][4];
  for (int i = 0; i < 4; ++i)
    for (int j = 0; j < 4; ++j) acc[i][j] = (floatx4){0.f, 0.f, 0.f, 0.f};

  auto stage = [&](int k0, int buf) {
    for (int i = 0; i < 2; ++i) {
      int c = i * 256 + tid;
      int row = c >> 2, off = (c & 3) * 8;
      gload_lds16(A + (m0 + row) * (size_t)lda + k0 + off, &As[buf][c * 8]);
      gload_lds16(Bt + (n0 + row) * (size_t)ldb + k0 + off, &Bs[buf][c * 8]);
    }
  };

  const int nk = K >> 5;
  stage(0, 0);
  __syncthreads();

  for (int ki = 0; ki < nk; ++ki) {
    const int buf = ki & 1;
    if (ki + 1 < nk) stage((ki + 1) << 5, buf ^ 1);

    short8 a[4], bb[4];
    for (int im = 0; im < 4; ++im)
      a[im] = *(const short8*)&As[buf][(wm * 64 + im * 16 + l16) * 32 + quad * 8];
    for (int in = 0; in < 4; ++in)
      bb[in] = *(const short8*)&Bs[buf][(wn * 64 + in * 16 + l16) * 32 + quad * 8];
    for (int im = 0; im < 4; ++im)
      for (int in = 0; in < 4; ++in)
        acc[im][in] = __builtin_amdgcn_mfma_f32_16x16x32_bf16(a[im], bb[in], acc[im][in], 0, 0, 0);

    __syncthreads();
  }

  for (int im = 0; im < 4; ++im)
    for (int in = 0; in < 4; ++in) {
      size_t r0 = m0 + wm * 64 + im * 16 + quad * 4;
      size_t col = n0 + wn * 64 + in * 16 + l16;
      float bv = (MODE == 1) ? bias[col] : 0.f;
      for (int r = 0; r < 4; ++r) {
        float val = acc[im][in][r] + bv;
        if (MODE == 0) {
          ((u16*)Cv)[(r0 + r) * (size_t)ldc + col] = f2bf(val);
        } else if (MODE == 1) {
          ((float*)Cv)[(r0 + r) * (size_t)ldc + col] = val;
        } else {
          int row = (int)(r0 + r);
          size_t ncol = (col & ~(size_t)63) | (size_t)vscr(row, (int)(col & 63));
          ((u16*)Cv)[row * (size_t)ldc + ncol] = f2bf(val);
        }
      }
    }
}

// ---- bf16 MFMA GEMM, 256^2 8-phase (T1+T2+T3+T4+T5): QK only ---------------
// (R9: best for the fat 256-block QK shape; worse than 128^2 for skinny.)
// vmcnt(0) on last-iter p3 is the race fix for the skipped p2/p3 stages.
__global__ __launch_bounds__(512, 2) void gemm256_bt(
    const u16* __restrict__ A, const u16* __restrict__ Bt, u16* __restrict__ C,
    int K, int lda, int ldb, int ldc) {
  __shared__ u16 As[2][256 * 64];
  __shared__ u16 Bs[2][256 * 64];
  const int tid = threadIdx.x;
  const int l = tid & 63, quad = l >> 4, l16 = l & 15;
  const int w = tid >> 6, wm = w >> 2, wn = w & 3;

  const int orig = blockIdx.x + 8 * blockIdx.y;
  const int tsw = (orig & 7) * 32 + (orig >> 3);
  const size_t m0 = (size_t)(tsw >> 3) * 256, n0 = (size_t)(tsw & 7) * 256;
  const int NT = K >> 6;

  floatx4 acc[8][4];
#pragma unroll
  for (int i = 0; i < 8; ++i)
#pragma unroll
    for (int j = 0; j < 4; ++j) acc[i][j] = (floatx4){0.f, 0.f, 0.f, 0.f};

  auto stage = [&](int isB, int t, int h) {
    const u16* src = isB ? Bt : A;
    const size_t rb = isB ? n0 : m0;
    const int ld = isB ? ldb : lda;
    u16* lds = (isB ? &Bs[t & 1][0] : &As[t & 1][0]) + h * 8192;
    const int k0 = t << 6;
#pragma unroll
    for (int r = 0; r < 2; ++r) {
      int idx = r * 512 + tid;
      int rr = idx >> 3;
      int ce = ((idx & 7) ^ (rr & 7)) << 3;
      gload_lds16(src + (rb + h * 128 + rr) * (size_t)ld + k0 + ce, lds + idx * 8);
    }
  };

  const int swz = (l16 & 7) << 4;
  const int ca0 = (quad * 16) ^ swz;
  const int ca1 = (64 + quad * 16) ^ swz;
  const char* aB = (const char*)&As[0][0];
  const char* bB = (const char*)&Bs[0][0];
  const int arow = (wm * 128 + l16) * 128;
  const int brow = (wn * 64 + l16) * 128;

  short8 a[4][2], b[2][2][2];

  auto readA = [&](int buf, int mh) {
#pragma unroll
    for (int ii = 0; ii < 4; ++ii) {
      const char* p = aB + buf * 32768 + arow + mh * 8192 + ii * 2048;
      a[ii][0] = *(const short8*)(p + ca0);
      a[ii][1] = *(const short8*)(p + ca1);
    }
  };
  auto readB = [&](int buf, int nh) {
#pragma unroll
    for (int jj = 0; jj < 2; ++jj) {
      const char* p = bB + buf * 32768 + brow + nh * 4096 + jj * 2048;
      b[nh][jj][0] = *(const short8*)(p + ca0);
      b[nh][jj][1] = *(const short8*)(p + ca1);
    }
  };
  auto mmaq = [&](int mh, int nh) {
    __builtin_amdgcn_s_setprio(1);
#pragma unroll
    for (int ii = 0; ii < 4; ++ii)
#pragma unroll
      for (int jj = 0; jj < 2; ++jj) {
        acc[mh * 4 + ii][nh * 2 + jj] = __builtin_amdgcn_mfma_f32_16x16x32_bf16(
            a[ii][0], b[nh][jj][0], acc[mh * 4 + ii][nh * 2 + jj], 0, 0, 0);
        acc[mh * 4 + ii][nh * 2 + jj] = __builtin_amdgcn_mfma_f32_16x16x32_bf16(
            a[ii][1], b[nh][jj][1], acc[mh * 4 + ii][nh * 2 + jj], 0, 0, 0);
      }
    __builtin_amdgcn_s_setprio(0);
  };

  stage(1, 0, 0); stage(1, 0, 1); stage(0, 0, 0); stage(0, 0, 1);
  stage(1, 1, 0); stage(1, 1, 1);
  VM4;
  BAR;

  const int nit = NT >> 1;
  for (int i = 0; i < nit; ++i) {
    const int t0 = 2 * i;
    const bool last = (i + 1 == nit);
    // p0
    readA(0, 0); readB(0, 0);
    stage(0, t0 + 1, 0);
    BAR; LGK0; mmaq(0, 0); BAR;
    // p1
    readB(0, 1);
    stage(0, t0 + 1, 1);
    BAR; LGK0; mmaq(0, 1); BAR;
    // p2
    readA(0, 1);
    if (t0 + 2 < NT) stage(1, t0 + 2, 0);
    BAR; LGK0; mmaq(1, 1); BAR;
    // p3
    if (t0 + 2 < NT) stage(1, t0 + 2, 1);
    mmaq(1, 0);
    if (last) { VM0; } else { VM4; }
    BAR;
    // p4
    readA(1, 0); readB(1, 0);
    if (t0 + 2 < NT) stage(0, t0 + 2, 0);
    BAR; LGK0; mmaq(0, 0); BAR;
    // p5
    readB(1, 1);
    if (t0 + 2 < NT) stage(0, t0 + 2, 1);
    BAR; LGK0; mmaq(0, 1); BAR;
    // p6
    readA(1, 1);
    if (t0 + 3 < NT) stage(1, t0 + 3, 0);
    BAR; LGK0; mmaq(1, 1); BAR;
    // p7
    if (t0 + 3 < NT) stage(1, t0 + 3, 1);
    mmaq(1, 0);
    VM4; BAR;
  }

#pragma unroll
  for (int iF = 0; iF < 8; ++iF)
#pragma unroll
    for (int jF = 0; jF < 4; ++jF) {
      size_t r0 = m0 + wm * 128 + iF * 16 + quad * 4;
      size_t col = n0 + wn * 64 + jF * 16 + l16;
#pragma unroll
      for (int r = 0; r < 4; ++r)
        C[(r0 + r) * (size_t)ldc + col] = f2bf(acc[iF][jF][r]);
    }
}

// ---- flash attention v8: v6 body + counted-vmcnt loop skeleton (T4) --------
// R11 pipe accounting: LDS-read is the binding pipe; the one skeleton cost
// left is the implicit vmcnt(0) drain inside v6's per-step __syncthreads(),
// which stalls every wave on the JUST-ISSUED stage(kt+1) loads. New skeleton
// per step: BAR (close prev reads of buf^1) ; stage(kt+1)->buf^1 ; vmcnt(2)
// (retires tile-kt's 2 loads; kt+1's stay in flight) ; BAR ; sched_barrier ;
// compute(buf). FIFO check: enter step with 2 outstanding (tile kt), issue +2
// (kt+1), vmcnt(2) leaves exactly kt+1's. Last step: vmcnt(0). Pre-loop aq
// loads are oldest and retire first — guarantee order-independent. Compute
// body, stage math, epilogue byte-identical to R7/R11-passing v6.
// qt = 15 - y: LONGEST BLOCKS DISPATCH FIRST (R10: do not permute).
// QK: bf16 [8192][2048] (Q pre-scaled cols 0..1023, K cols 1024..2047).
// Vt: bf16 [1024][8192], V-SCRAMBLED within 64-k chunks (see vscr).
// ctx: bf16 [8192][1024].
// K LDS swizzle: byte(row,col2B) = row*128 + ((2*col) ^ ((row&7)<<4)).
// V LDS: linear copy of scrambled global -> va ds_read_b64 conflict-free.
__global__ __launch_bounds__(512, 4) void flash_attn(
    const u16* __restrict__ QK, const u16* __restrict__ Vt, u16* __restrict__ ctx) {
  __shared__ u16 Ks[2][64 * 64];
  __shared__ u16 Vs[2][64 * 64];

  const int tid = threadIdx.x;
  const int w = tid >> 6, l = tid & 63, quad = l >> 4, l16 = l & 15;
  const int bh = blockIdx.x;
  const int qt = 15 - blockIdx.y;           // descending: long blocks first
  const int b = bh >> 4, h = bh & 15;
  const int xr = (l16 & 7) << 4;
  const int xv = (2 * (l16 & 7)) ^ ((l16 >> 3) & 1);   // V kappa-xor per lane

  const int nkt = 2 * qt + 2;

  auto stage = [&](int kt, int buf) {
    int c = tid;                            // 512 thr x 16B = one 8KB buffer
    int row = c >> 3;
    int scolK = ((c & 7) ^ (row & 7)) << 3;
    gload_lds16(QK + (size_t)(b * 2048 + kt * 64 + row) * 2048 + 1024 + h * 64 + scolK,
                &Ks[buf][c * 8]);
    // V: scramble baked into global layout -> linear source
    gload_lds16(Vt + (size_t)(h * 64 + row) * 8192 + b * 2048 + kt * 64 + ((c & 7) << 3),
                &Vs[buf][c * 8]);
  };

  const int q0w = qt * 128 + w * 16;
  const int ktmax_w = (q0w + 15) >> 6;

  short8 aq[2];
  floatx4 o[4];
  float lsum;
  {
    const size_t base = (size_t)(b * 2048 + q0w + l16) * 2048 + h * 64 + quad * 8;
    aq[0] = *(const short8*)(QK + base);
    aq[1] = *(const short8*)(QK + base + 32);
    lsum = 0.f;
    for (int df = 0; df < 4; ++df) o[df] = (floatx4){0.f, 0.f, 0.f, 0.f};
  }

  stage(0, 0);   // 2 loads outstanding entering the loop

  for (int kt = 0; kt < nkt; ++kt) {
    const int buf = kt & 1;
    BAR;                                     // close prev step's reads of buf^1
    if (kt + 1 < nkt) {
      stage(kt + 1, buf ^ 1);                // +2 loads (newest)
      VM2;                                   // tile-kt's 2 loads retired
    } else {
      VM0;                                   // final tile: full drain
    }
    BAR;                                     // all waves' tile-kt data in LDS
    __builtin_amdgcn_sched_barrier(0);       // rule #18: pin reads after waits

    if (kt <= ktmax_w) {
      const bool need_mask = (kt == ktmax_w);

      short8 ka[4][2];
      for (int nf = 0; nf < 4; ++nf) {
        const char* kb = (const char*)&Ks[buf][0] + (nf * 16 + l16) * 128;
        ka[nf][0] = *(const short8*)(kb + ((quad * 16) ^ xr));
        ka[nf][1] = *(const short8*)(kb + ((64 + quad * 16) ^ xr));
      }

      floatx4 s[4];
      for (int nf = 0; nf < 4; ++nf) s[nf] = (floatx4){0.f, 0.f, 0.f, 0.f};
      __builtin_amdgcn_s_setprio(1);
      for (int nf = 0; nf < 4; ++nf) {
        s[nf] = __builtin_amdgcn_mfma_f32_16x16x32_bf16(ka[nf][0], aq[0], s[nf], 0, 0, 0);
        s[nf] = __builtin_amdgcn_mfma_f32_16x16x32_bf16(ka[nf][1], aq[1], s[nf], 0, 0, 0);
      }
      __builtin_amdgcn_s_setprio(0);
      if (need_mask) {
        int qpos = q0w + l16;
        for (int nf = 0; nf < 4; ++nf)
          for (int r = 0; r < 4; ++r) {
            int kpos = kt * 64 + nf * 16 + quad * 4 + r;
            if (kpos > qpos) s[nf][r] = -1e30f;
          }
      }
      for (int nf = 0; nf < 4; ++nf) {
        // V^T A-frags: lane holds Vs[d = df*16+l16][k = nf*16 + quad*4 + j]
        // at scrambled byte offset ((nf*4+quad) ^ xv) * 8.
        const int kpp = ((nf * 4 + quad) ^ xv) << 3;
        short4_t va[4];
        for (int df = 0; df < 4; ++df) {
          const char* vb = (const char*)&Vs[buf][0] + (df * 16 + l16) * 128;
          va[df] = *(const short4_t*)(vb + kpp);
        }
        float p0 = __builtin_amdgcn_exp2f(s[nf][0]);
        float p1 = __builtin_amdgcn_exp2f(s[nf][1]);
        float p2 = __builtin_amdgcn_exp2f(s[nf][2]);
        float p3 = __builtin_amdgcn_exp2f(s[nf][3]);
        lsum += (p0 + p1) + (p2 + p3);
        uint2_t pk;
        pk.x = cvt_pk_bf16(p0, p1);   // lo16 = p0 (j even), hi = p1
        pk.y = cvt_pk_bf16(p2, p3);
        short4_t pb = __builtin_bit_cast(short4_t, pk);  // B-frag of 16x16x16
        __builtin_amdgcn_s_setprio(1);
        for (int df = 0; df < 4; ++df)
          o[df] = __builtin_amdgcn_mfma_f32_16x16x16bf16_1k(va[df], pb, o[df], 0, 0, 0);
        __builtin_amdgcn_s_setprio(0);
      }
    }
  }

  {
    float t = lsum;
    t += __shfl_xor(t, 16, 64);
    t += __shfl_xor(t, 32, 64);
    float inv = __builtin_amdgcn_rcpf(t);
    // o^T: lane q = l16, d = df*16 + quad*4 + r  -> in-lane normalize
    size_t row = (size_t)(b * 2048 + q0w + l16);
    for (int df = 0; df < 4; ++df) {
      ushort4_t st;
      for (int r = 0; r < 4; ++r) st[r] = f2bf(o[df][r] * inv);
      *(ushort4_t*)(ctx + row * 1024 + h * 64 + df * 16 + quad * 4) = st;
    }
  }
}

// ---- launch ----------------------------------------------------------------

extern "C" void kernel_launch(void* const* d_in, const int* in_sizes, int n_in,
                              void* d_out, int out_size, void* d_ws, size_t ws_size,
                              hipStream_t stream) {
  const float* X  = (const float*)d_in[0];
  const float* Wq = (const float*)d_in[1];
  const float* Wk = (const float*)d_in[2];
  const float* Wv = (const float*)d_in[3];
  const float* Wo = (const float*)d_in[4];
  const float* bo = (const float*)d_in[5];

  char* ws = (char*)d_ws;
  u16* Xb   = (u16*)(ws);                  // 16 MiB; later overwritten with ctx
  u16* WqkT = (u16*)(ws + (16u << 20));    // 4 MiB: [Wq^T(scaled) ; Wk^T]
  u16* WvT  = (u16*)(ws + (20u << 20));    // 2 MiB
  u16* WoT  = (u16*)(ws + (22u << 20));    // 2 MiB
  u16* QKb  = (u16*)(ws + (24u << 20));    // 32 MiB: [8192][2048]
  u16* Vt   = (u16*)(ws + (56u << 20));    // 16 MiB: [1024][8192] (V-scrambled)

  const float SC = 0.125f * 1.44269504088896340736f;  // 1/sqrt(64) * log2(e)

  cvt_x<<<8192, 256, 0, stream>>>(X, Xb);
  transpose_cvt4<<<dim3(16, 16, 4), 256, 0, stream>>>(Wq, Wk, Wv, Wo, WqkT, WvT, WoT, SC);

  // [Q K] = Xb @ [Wq Wk] : [8192][2048]  -- 256^2 8-phase, 256 blocks
  gemm256_bt<<<dim3(8, 32), 512, 0, stream>>>(Xb, WqkT, QKb, 1024, 1024, 1024, 2048);
  // Vt = (Xb @ Wv)^T : [1024][8192], V-scrambled -- 128^2, 512 blocks
  gemm_bt<2><<<dim3(64, 8), 256, 0, stream>>>(WvT, Xb, Vt, nullptr, 1024, 1024, 1024, 8192);

  // causal flash attention v8 (counted-vmcnt skeleton); ctx overwrites Xb
  flash_attn<<<dim3(64, 16), 512, 0, stream>>>(QKb, Vt, Xb);

  // out = ctx @ Wo + bo : fp32 -- 128^2, 512 blocks
  gemm_bt<1><<<dim3(8, 64), 256, 0, stream>>>(Xb, WoT, (float*)d_out, bo, 1024, 1024, 1024, 1024);
}

// Round 14
// 236.762 us; speedup vs baseline: 1.0925x; 1.0096x over previous
//
#include <hip/hip_runtime.h>

typedef unsigned short u16;
typedef unsigned int u32;
typedef __attribute__((ext_vector_type(8))) short short8;
typedef __attribute__((ext_vector_type(4))) short short4_t;
typedef __attribute__((ext_vector_type(4))) float floatx4;
typedef __attribute__((ext_vector_type(4))) unsigned short ushort4_t;
typedef __attribute__((ext_vector_type(4))) float float4_t;
typedef __attribute__((ext_vector_type(2))) unsigned int uint2_t;

// ---- helpers ---------------------------------------------------------------

__device__ __forceinline__ u16 f2bf(float f) {
  unsigned u = __builtin_bit_cast(unsigned, f);
  u += 0x7FFFu + ((u >> 16) & 1u);   // RNE; inputs finite
  return (u16)(u >> 16);
}

// pack two fp32 -> bf16x2 via HW cvt_pk (RNE on gfx950): lo16 = a, hi16 = b
__device__ __forceinline__ u32 cvt_pk_bf16(float a, float b) {
  u32 r;
  asm("v_cvt_pk_bf16_f32 %0, %1, %2" : "=v"(r) : "v"(a), "v"(b));
  return r;
}

// async global->LDS, 16B per lane. LDS dest must be wave-uniform base + lane*16.
__device__ __forceinline__ void gload_lds16(const void* g, void* l) {
  __builtin_amdgcn_global_load_lds(
      (const __attribute__((address_space(1))) void*)g,
      (__attribute__((address_space(3))) void*)l, 16, 0, 0);
}

#define BAR __builtin_amdgcn_s_barrier()
#define LGK0                                              \
  do {                                                    \
    asm volatile("s_waitcnt lgkmcnt(0)" ::: "memory");    \
    __builtin_amdgcn_sched_barrier(0);                    \
  } while (0)
#define VM4 asm volatile("s_waitcnt vmcnt(4)" ::: "memory")
#define VM2 asm volatile("s_waitcnt vmcnt(2)" ::: "memory")
#define VM0 asm volatile("s_waitcnt vmcnt(0)" ::: "memory")

// V-scramble: within each 64-elem k-chunk of row d, 4-elem group kappa moves
// to kappa ^ (2*(d&7)) ^ ((d>>3)&1). The parity term makes the 8B-half of a
// lane's va read vary with l16 bit 3 -> ds_read_b64 touches all 32 banks
// within each 16-lane processing group (verified: conflicts 8.65M -> 0).
__device__ __forceinline__ int vscr(int d, int c6) {
  int kp = (c6 >> 2) ^ (2 * (d & 7)) ^ ((d >> 3) & 1);
  return kp * 4 + (c6 & 3);
}

// ---- fused prep: cvt_x (blocks 0..8191) + transpose_cvt4 (8192..9215) ------
// Bodies identical to the bench-proven standalone kernels; block-uniform
// routing only. Saves one launch gap and overlaps the small transpose under
// cvt_x's HBM streaming.
__global__ __launch_bounds__(256) void prep_fused(
    const float* __restrict__ X, u16* __restrict__ Xb,
    const float* __restrict__ wq, const float* __restrict__ wk,
    const float* __restrict__ wv, const float* __restrict__ wo,
    u16* __restrict__ qk, u16* __restrict__ vt, u16* __restrict__ ot, float sc) {
  __shared__ float T[64][65];
  const int bid = blockIdx.x;
  if (bid < 8192) {
    // X fp32 [8192][1024] -> bf16
    int i = bid * 256 + threadIdx.x;
    float4_t f = ((const float4_t*)X)[i];
    ushort4_t u;
    u.x = f2bf(f.x); u.y = f2bf(f.y); u.z = f2bf(f.z); u.w = f2bf(f.w);
    ((ushort4_t*)Xb)[i] = u;
  } else {
    // coalesced LDS-tiled transpose+cvt: W fp32 [K][N] -> bf16 [N][K].
    const int t = bid - 8192;                 // maps (16,16,4) grid
    const int which = t >> 8;
    const float* s = (which == 0) ? wq : (which == 1) ? wk : (which == 2) ? wv : wo;
    u16* d = (which == 0) ? qk : (which == 1) ? (qk + (1u << 20)) : (which == 2) ? vt : ot;
    const float scale = (which == 0) ? sc : 1.f;
    const int n0 = (t & 15) * 64, k0 = ((t >> 4) & 15) * 64;
    const int c = threadIdx.x & 63, rg = threadIdx.x >> 6;
    for (int i = 0; i < 16; ++i) {
      int r = i * 4 + rg;
      T[r][c] = s[(k0 + r) * 1024 + n0 + c];
    }
    __syncthreads();
    for (int i = 0; i < 16; ++i) {
      int r = i * 4 + rg;
      d[(n0 + r) * 1024 + k0 + c] = f2bf(T[c][r] * scale);
    }
  }
}

// ---- bf16 MFMA GEMM (128^2 m97-structure): for skinny shapes (R9 lesson:
// at 512 full-GPU blocks this beats the 128-block 256^2 kernel for Vt/out).
// MODE 0: bf16 out. MODE 1: f32 out + bias. MODE 2: bf16 out, V-scrambled cols.
template <int MODE>
__global__ __launch_bounds__(256) void gemm_bt(
    const u16* __restrict__ A, const u16* __restrict__ Bt, void* __restrict__ Cv,
    const float* __restrict__ bias, int K, int lda, int ldb, int ldc) {
  __shared__ u16 As[2][128 * 32];
  __shared__ u16 Bs[2][128 * 32];
  const int tid = threadIdx.x;
  const int w = tid >> 6, l = tid & 63, quad = l >> 4, l16 = l & 15;
  const int wm = w >> 1, wn = w & 1;
  const size_t m0 = (size_t)blockIdx.y * 128, n0 = (size_t)blockIdx.x * 128;

  floatx4 acc[4][4];
  for (int i = 0; i < 4; ++i)
    for (int j = 0; j < 4; ++j) acc[i][j] = (floatx4){0.f, 0.f, 0.f, 0.f};

  auto stage = [&](int k0, int buf) {
    for (int i = 0; i < 2; ++i) {
      int c = i * 256 + tid;
      int row = c >> 2, off = (c & 3) * 8;
      gload_lds16(A + (m0 + row) * (size_t)lda + k0 + off, &As[buf][c * 8]);
      gload_lds16(Bt + (n0 + row) * (size_t)ldb + k0 + off, &Bs[buf][c * 8]);
    }
  };

  const int nk = K >> 5;
  stage(0, 0);
  __syncthreads();

  for (int ki = 0; ki < nk; ++ki) {
    const int buf = ki & 1;
    if (ki + 1 < nk) stage((ki + 1) << 5, buf ^ 1);

    short8 a[4], bb[4];
    for (int im = 0; im < 4; ++im)
      a[im] = *(const short8*)&As[buf][(wm * 64 + im * 16 + l16) * 32 + quad * 8];
    for (int in = 0; in < 4; ++in)
      bb[in] = *(const short8*)&Bs[buf][(wn * 64 + in * 16 + l16) * 32 + quad * 8];
    for (int im = 0; im < 4; ++im)
      for (int in = 0; in < 4; ++in)
        acc[im][in] = __builtin_amdgcn_mfma_f32_16x16x32_bf16(a[im], bb[in], acc[im][in], 0, 0, 0);

    __syncthreads();
  }

  for (int im = 0; im < 4; ++im)
    for (int in = 0; in < 4; ++in) {
      size_t r0 = m0 + wm * 64 + im * 16 + quad * 4;
      size_t col = n0 + wn * 64 + in * 16 + l16;
      float bv = (MODE == 1) ? bias[col] : 0.f;
      for (int r = 0; r < 4; ++r) {
        float val = acc[im][in][r] + bv;
        if (MODE == 0) {
          ((u16*)Cv)[(r0 + r) * (size_t)ldc + col] = f2bf(val);
        } else if (MODE == 1) {
          ((float*)Cv)[(r0 + r) * (size_t)ldc + col] = val;
        } else {
          int row = (int)(r0 + r);
          size_t ncol = (col & ~(size_t)63) | (size_t)vscr(row, (int)(col & 63));
          ((u16*)Cv)[row * (size_t)ldc + ncol] = f2bf(val);
        }
      }
    }
}

// ---- bf16 MFMA GEMM, 256^2 8-phase (T1+T2+T3+T4+T5): QK only ---------------
// (R9: best for the fat 256-block QK shape; worse than 128^2 for skinny.)
// vmcnt(0) on last-iter p3 is the race fix for the skipped p2/p3 stages.
__global__ __launch_bounds__(512, 2) void gemm256_bt(
    const u16* __restrict__ A, const u16* __restrict__ Bt, u16* __restrict__ C,
    int K, int lda, int ldb, int ldc) {
  __shared__ u16 As[2][256 * 64];
  __shared__ u16 Bs[2][256 * 64];
  const int tid = threadIdx.x;
  const int l = tid & 63, quad = l >> 4, l16 = l & 15;
  const int w = tid >> 6, wm = w >> 2, wn = w & 3;

  const int orig = blockIdx.x + 8 * blockIdx.y;
  const int tsw = (orig & 7) * 32 + (orig >> 3);
  const size_t m0 = (size_t)(tsw >> 3) * 256, n0 = (size_t)(tsw & 7) * 256;
  const int NT = K >> 6;

  floatx4 acc[8][4];
#pragma unroll
  for (int i = 0; i < 8; ++i)
#pragma unroll
    for (int j = 0; j < 4; ++j) acc[i][j] = (floatx4){0.f, 0.f, 0.f, 0.f};

  auto stage = [&](int isB, int t, int h) {
    const u16* src = isB ? Bt : A;
    const size_t rb = isB ? n0 : m0;
    const int ld = isB ? ldb : lda;
    u16* lds = (isB ? &Bs[t & 1][0] : &As[t & 1][0]) + h * 8192;
    const int k0 = t << 6;
#pragma unroll
    for (int r = 0; r < 2; ++r) {
      int idx = r * 512 + tid;
      int rr = idx >> 3;
      int ce = ((idx & 7) ^ (rr & 7)) << 3;
      gload_lds16(src + (rb + h * 128 + rr) * (size_t)ld + k0 + ce, lds + idx * 8);
    }
  };

  const int swz = (l16 & 7) << 4;
  const int ca0 = (quad * 16) ^ swz;
  const int ca1 = (64 + quad * 16) ^ swz;
  const char* aB = (const char*)&As[0][0];
  const char* bB = (const char*)&Bs[0][0];
  const int arow = (wm * 128 + l16) * 128;
  const int brow = (wn * 64 + l16) * 128;

  short8 a[4][2], b[2][2][2];

  auto readA = [&](int buf, int mh) {
#pragma unroll
    for (int ii = 0; ii < 4; ++ii) {
      const char* p = aB + buf * 32768 + arow + mh * 8192 + ii * 2048;
      a[ii][0] = *(const short8*)(p + ca0);
      a[ii][1] = *(const short8*)(p + ca1);
    }
  };
  auto readB = [&](int buf, int nh) {
#pragma unroll
    for (int jj = 0; jj < 2; ++jj) {
      const char* p = bB + buf * 32768 + brow + nh * 4096 + jj * 2048;
      b[nh][jj][0] = *(const short8*)(p + ca0);
      b[nh][jj][1] = *(const short8*)(p + ca1);
    }
  };
  auto mmaq = [&](int mh, int nh) {
    __builtin_amdgcn_s_setprio(1);
#pragma unroll
    for (int ii = 0; ii < 4; ++ii)
#pragma unroll
      for (int jj = 0; jj < 2; ++jj) {
        acc[mh * 4 + ii][nh * 2 + jj] = __builtin_amdgcn_mfma_f32_16x16x32_bf16(
            a[ii][0], b[nh][jj][0], acc[mh * 4 + ii][nh * 2 + jj], 0, 0, 0);
        acc[mh * 4 + ii][nh * 2 + jj] = __builtin_amdgcn_mfma_f32_16x16x32_bf16(
            a[ii][1], b[nh][jj][1], acc[mh * 4 + ii][nh * 2 + jj], 0, 0, 0);
      }
    __builtin_amdgcn_s_setprio(0);
  };

  stage(1, 0, 0); stage(1, 0, 1); stage(0, 0, 0); stage(0, 0, 1);
  stage(1, 1, 0); stage(1, 1, 1);
  VM4;
  BAR;

  const int nit = NT >> 1;
  for (int i = 0; i < nit; ++i) {
    const int t0 = 2 * i;
    const bool last = (i + 1 == nit);
    // p0
    readA(0, 0); readB(0, 0);
    stage(0, t0 + 1, 0);
    BAR; LGK0; mmaq(0, 0); BAR;
    // p1
    readB(0, 1);
    stage(0, t0 + 1, 1);
    BAR; LGK0; mmaq(0, 1); BAR;
    // p2
    readA(0, 1);
    if (t0 + 2 < NT) stage(1, t0 + 2, 0);
    BAR; LGK0; mmaq(1, 1); BAR;
    // p3
    if (t0 + 2 < NT) stage(1, t0 + 2, 1);
    mmaq(1, 0);
    if (last) { VM0; } else { VM4; }
    BAR;
    // p4
    readA(1, 0); readB(1, 0);
    if (t0 + 2 < NT) stage(0, t0 + 2, 0);
    BAR; LGK0; mmaq(0, 0); BAR;
    // p5
    readB(1, 1);
    if (t0 + 2 < NT) stage(0, t0 + 2, 1);
    BAR; LGK0; mmaq(0, 1); BAR;
    // p6
    readA(1, 1);
    if (t0 + 3 < NT) stage(1, t0 + 3, 0);
    BAR; LGK0; mmaq(1, 1); BAR;
    // p7
    if (t0 + 3 < NT) stage(1, t0 + 3, 1);
    mmaq(1, 0);
    VM4; BAR;
  }

#pragma unroll
  for (int iF = 0; iF < 8; ++iF)
#pragma unroll
    for (int jF = 0; jF < 4; ++jF) {
      size_t r0 = m0 + wm * 128 + iF * 16 + quad * 4;
      size_t col = n0 + wn * 64 + jF * 16 + l16;
#pragma unroll
      for (int r = 0; r < 4; ++r)
        C[(r0 + r) * (size_t)ldc + col] = f2bf(acc[iF][jF][r]);
    }
}

// ---- flash attention v8 (R13-proven, 53.8-54.2 us): counted-vmcnt skeleton -
// Per step: BAR (close prev reads of buf^1) ; stage(kt+1)->buf^1 ; vmcnt(2)
// (retires tile-kt's loads; kt+1's stay in flight) ; BAR ; sched_barrier ;
// compute(buf). Last step: vmcnt(0). R13 measured: MfmaUtil 37->40, -3 us.
// qt = 15 - y: LONGEST BLOCKS DISPATCH FIRST (R10: do not permute).
// QK: bf16 [8192][2048] (Q pre-scaled cols 0..1023, K cols 1024..2047).
// Vt: bf16 [1024][8192], V-SCRAMBLED within 64-k chunks (see vscr).
// ctx: bf16 [8192][1024].
// K LDS swizzle: byte(row,col2B) = row*128 + ((2*col) ^ ((row&7)<<4)).
// V LDS: linear copy of scrambled global -> va ds_read_b64 conflict-free.
__global__ __launch_bounds__(512, 4) void flash_attn(
    const u16* __restrict__ QK, const u16* __restrict__ Vt, u16* __restrict__ ctx) {
  __shared__ u16 Ks[2][64 * 64];
  __shared__ u16 Vs[2][64 * 64];

  const int tid = threadIdx.x;
  const int w = tid >> 6, l = tid & 63, quad = l >> 4, l16 = l & 15;
  const int bh = blockIdx.x;
  const int qt = 15 - blockIdx.y;           // descending: long blocks first
  const int b = bh >> 4, h = bh & 15;
  const int xr = (l16 & 7) << 4;
  const int xv = (2 * (l16 & 7)) ^ ((l16 >> 3) & 1);   // V kappa-xor per lane

  const int nkt = 2 * qt + 2;

  auto stage = [&](int kt, int buf) {
    int c = tid;                            // 512 thr x 16B = one 8KB buffer
    int row = c >> 3;
    int scolK = ((c & 7) ^ (row & 7)) << 3;
    gload_lds16(QK + (size_t)(b * 2048 + kt * 64 + row) * 2048 + 1024 + h * 64 + scolK,
                &Ks[buf][c * 8]);
    // V: scramble baked into global layout -> linear source
    gload_lds16(Vt + (size_t)(h * 64 + row) * 8192 + b * 2048 + kt * 64 + ((c & 7) << 3),
                &Vs[buf][c * 8]);
  };

  const int q0w = qt * 128 + w * 16;
  const int ktmax_w = (q0w + 15) >> 6;

  short8 aq[2];
  floatx4 o[4];
  float lsum;
  {
    const size_t base = (size_t)(b * 2048 + q0w + l16) * 2048 + h * 64 + quad * 8;
    aq[0] = *(const short8*)(QK + base);
    aq[1] = *(const short8*)(QK + base + 32);
    lsum = 0.f;
    for (int df = 0; df < 4; ++df) o[df] = (floatx4){0.f, 0.f, 0.f, 0.f};
  }

  stage(0, 0);   // 2 loads outstanding entering the loop

  for (int kt = 0; kt < nkt; ++kt) {
    const int buf = kt & 1;
    BAR;                                     // close prev step's reads of buf^1
    if (kt + 1 < nkt) {
      stage(kt + 1, buf ^ 1);                // +2 loads (newest)
      VM2;                                   // tile-kt's 2 loads retired
    } else {
      VM0;                                   // final tile: full drain
    }
    BAR;                                     // all waves' tile-kt data in LDS
    __builtin_amdgcn_sched_barrier(0);       // rule #18: pin reads after waits

    if (kt <= ktmax_w) {
      const bool need_mask = (kt == ktmax_w);

      short8 ka[4][2];
      for (int nf = 0; nf < 4; ++nf) {
        const char* kb = (const char*)&Ks[buf][0] + (nf * 16 + l16) * 128;
        ka[nf][0] = *(const short8*)(kb + ((quad * 16) ^ xr));
        ka[nf][1] = *(const short8*)(kb + ((64 + quad * 16) ^ xr));
      }

      floatx4 s[4];
      for (int nf = 0; nf < 4; ++nf) s[nf] = (floatx4){0.f, 0.f, 0.f, 0.f};
      __builtin_amdgcn_s_setprio(1);
      for (int nf = 0; nf < 4; ++nf) {
        s[nf] = __builtin_amdgcn_mfma_f32_16x16x32_bf16(ka[nf][0], aq[0], s[nf], 0, 0, 0);
        s[nf] = __builtin_amdgcn_mfma_f32_16x16x32_bf16(ka[nf][1], aq[1], s[nf], 0, 0, 0);
      }
      __builtin_amdgcn_s_setprio(0);
      if (need_mask) {
        int qpos = q0w + l16;
        for (int nf = 0; nf < 4; ++nf)
          for (int r = 0; r < 4; ++r) {
            int kpos = kt * 64 + nf * 16 + quad * 4 + r;
            if (kpos > qpos) s[nf][r] = -1e30f;
          }
      }
      for (int nf = 0; nf < 4; ++nf) {
        // V^T A-frags: lane holds Vs[d = df*16+l16][k = nf*16 + quad*4 + j]
        // at scrambled byte offset ((nf*4+quad) ^ xv) * 8.
        const int kpp = ((nf * 4 + quad) ^ xv) << 3;
        short4_t va[4];
        for (int df = 0; df < 4; ++df) {
          const char* vb = (const char*)&Vs[buf][0] + (df * 16 + l16) * 128;
          va[df] = *(const short4_t*)(vb + kpp);
        }
        float p0 = __builtin_amdgcn_exp2f(s[nf][0]);
        float p1 = __builtin_amdgcn_exp2f(s[nf][1]);
        float p2 = __builtin_amdgcn_exp2f(s[nf][2]);
        float p3 = __builtin_amdgcn_exp2f(s[nf][3]);
        lsum += (p0 + p1) + (p2 + p3);
        uint2_t pk;
        pk.x = cvt_pk_bf16(p0, p1);   // lo16 = p0 (j even), hi = p1
        pk.y = cvt_pk_bf16(p2, p3);
        short4_t pb = __builtin_bit_cast(short4_t, pk);  // B-frag of 16x16x16
        __builtin_amdgcn_s_setprio(1);
        for (int df = 0; df < 4; ++df)
          o[df] = __builtin_amdgcn_mfma_f32_16x16x16bf16_1k(va[df], pb, o[df], 0, 0, 0);
        __builtin_amdgcn_s_setprio(0);
      }
    }
  }

  {
    float t = lsum;
    t += __shfl_xor(t, 16, 64);
    t += __shfl_xor(t, 32, 64);
    float inv = __builtin_amdgcn_rcpf(t);
    // o^T: lane q = l16, d = df*16 + quad*4 + r  -> in-lane normalize
    size_t row = (size_t)(b * 2048 + q0w + l16);
    for (int df = 0; df < 4; ++df) {
      ushort4_t st;
      for (int r = 0; r < 4; ++r) st[r] = f2bf(o[df][r] * inv);
      *(ushort4_t*)(ctx + row * 1024 + h * 64 + df * 16 + quad * 4) = st;
    }
  }
}

// ---- launch ----------------------------------------------------------------

extern "C" void kernel_launch(void* const* d_in, const int* in_sizes, int n_in,
                              void* d_out, int out_size, void* d_ws, size_t ws_size,
                              hipStream_t stream) {
  const float* X  = (const float*)d_in[0];
  const float* Wq = (const float*)d_in[1];
  const float* Wk = (const float*)d_in[2];
  const float* Wv = (const float*)d_in[3];
  const float* Wo = (const float*)d_in[4];
  const float* bo = (const float*)d_in[5];

  char* ws = (char*)d_ws;
  u16* Xb   = (u16*)(ws);                  // 16 MiB; later overwritten with ctx
  u16* WqkT = (u16*)(ws + (16u << 20));    // 4 MiB: [Wq^T(scaled) ; Wk^T]
  u16* WvT  = (u16*)(ws + (20u << 20));    // 2 MiB
  u16* WoT  = (u16*)(ws + (22u << 20));    // 2 MiB
  u16* QKb  = (u16*)(ws + (24u << 20));    // 32 MiB: [8192][2048]
  u16* Vt   = (u16*)(ws + (56u << 20));    // 16 MiB: [1024][8192] (V-scrambled)

  const float SC = 0.125f * 1.44269504088896340736f;  // 1/sqrt(64) * log2(e)

  // fused prep: cvt_x (8192 blocks) + 4x transpose (1024 blocks)
  prep_fused<<<9216, 256, 0, stream>>>(X, Xb, Wq, Wk, Wv, Wo, WqkT, WvT, WoT, SC);

  // [Q K] = Xb @ [Wq Wk] : [8192][2048]  -- 256^2 8-phase, 256 blocks
  gemm256_bt<<<dim3(8, 32), 512, 0, stream>>>(Xb, WqkT, QKb, 1024, 1024, 1024, 2048);
  // Vt = (Xb @ Wv)^T : [1024][8192], V-scrambled -- 128^2, 512 blocks
  gemm_bt<2><<<dim3(64, 8), 256, 0, stream>>>(WvT, Xb, Vt, nullptr, 1024, 1024, 1024, 8192);

  // causal flash attention v8 (counted-vmcnt skeleton); ctx overwrites Xb
  flash_attn<<<dim3(64, 16), 512, 0, stream>>>(QKb, Vt, Xb);

  // out = ctx @ Wo + bo : fp32 -- 128^2, 512 blocks
  gemm_bt<1><<<dim3(8, 64), 256, 0, stream>>>(Xb, WoT, (float*)d_out, bo, 1024, 1024, 1024, 1024);
}